// Round 1
// baseline (564.884 us; speedup 1.0000x reference)
//
#include <hip/hip_runtime.h>

// QuantizedLinear: out[M=4096, N=11008] = x[M,K=4096] @ (s*(q-zp))[N,K]^T
// Strategy: preconvert w->bf16 (dequantized) and x->bf16 into d_ws, then
// m97-structure bf16 MFMA GEMM (128x128 tile, BK=64, global_load_lds width=16,
// both-sides XOR swizzle). Fallback (ws too small): fused conversion staging.

#define M_DIM 4096
#define N_DIM 11008
#define K_DIM 4096
#define BM 128
#define BN 128
#define BK 64
#define NTILES_N (N_DIM / BN)   // 86
#define KT (K_DIM / BK)         // 64

typedef __attribute__((ext_vector_type(8))) short short8;  // 8 x bf16
typedef __attribute__((ext_vector_type(4))) float f32x4;

__device__ inline unsigned short f2bf(float f) {
  unsigned int u = __float_as_uint(f);
  u += 0x7FFFu + ((u >> 16) & 1u);   // round-to-nearest-even
  return (unsigned short)(u >> 16);
}

// ---- conversion pre-passes (memory-bound, vectorized 16B loads) ----

__global__ void cvt_w_kernel(const int* __restrict__ q, unsigned short* __restrict__ wb,
                             const float* __restrict__ sp, const float* __restrict__ zpp,
                             int n4) {
  const float s = *sp;
  const float nszp = -s * (*zpp);
  int stride = gridDim.x * blockDim.x;
  for (int i = blockIdx.x * blockDim.x + threadIdx.x; i < n4; i += stride) {
    int4 v = ((const int4*)q)[i];
    ushort4 o = make_ushort4(f2bf(fmaf(s, (float)v.x, nszp)),
                             f2bf(fmaf(s, (float)v.y, nszp)),
                             f2bf(fmaf(s, (float)v.z, nszp)),
                             f2bf(fmaf(s, (float)v.w, nszp)));
    ((ushort4*)wb)[i] = o;
  }
}

__global__ void cvt_x_kernel(const float* __restrict__ x, unsigned short* __restrict__ xb,
                             int n4) {
  int stride = gridDim.x * blockDim.x;
  for (int i = blockIdx.x * blockDim.x + threadIdx.x; i < n4; i += stride) {
    float4 v = ((const float4*)x)[i];
    ushort4 o = make_ushort4(f2bf(v.x), f2bf(v.y), f2bf(v.z), f2bf(v.w));
    ((ushort4*)xb)[i] = o;
  }
}

// ---- GEMM ----
// FUSED=false: Ap = x as bf16 [M][K], Bp = w as bf16 [N][K] (both from ws)
// FUSED=true : Ap = x fp32 [M][K], Bp = q int32 [N][K]; convert during staging
template <bool FUSED>
__global__ __launch_bounds__(256)
void qgemm(const void* __restrict__ Ap, const void* __restrict__ Bp,
           const float* __restrict__ sp, const float* __restrict__ zpp,
           float* __restrict__ C) {
  __shared__ unsigned short As[BM * BK];   // 16 KB, swizzled layout
  __shared__ unsigned short Bs[BN * BK];   // 16 KB

  // XCD-aware bijective swizzle (nwg = 2752, divisible by 8)
  int bid = blockIdx.x;
  {
    const int nwg = gridDim.x;
    if ((nwg & 7) == 0) {
      const int cpx = nwg >> 3;
      bid = (bid & 7) * cpx + (bid >> 3);
    }
  }
  const int mt = bid / NTILES_N;
  const int nt = bid % NTILES_N;

  const int tid  = threadIdx.x;
  const int wave = tid >> 6;
  const int lane = tid & 63;
  const int l15  = lane & 15;
  const int l4   = lane >> 4;
  const int wr   = wave >> 1;   // wave row (0..1) -> 64 output rows
  const int wc   = wave & 1;    // wave col (0..1) -> 64 output cols

  f32x4 acc[4][4];
#pragma unroll
  for (int m = 0; m < 4; ++m)
#pragma unroll
    for (int n = 0; n < 4; ++n) acc[m][n] = (f32x4)0.0f;

  // Fragment-read byte offsets into swizzled LDS.
  // Element (r, k): byte = r*128 + ((k*2) ^ ((r&7)<<4)); here r&7 == lane&7.
  const unsigned swzR  = (unsigned)(lane & 7) << 4;
  const unsigned aBase = (unsigned)(wr * 64 + l15) * (BK * 2);
  const unsigned bBase = (unsigned)(wc * 64 + l15) * (BK * 2);
  const unsigned kc0   = ((unsigned)(l4 * 16)) ^ swzR;        // kk = 0
  const unsigned kc1   = ((unsigned)(64 + l4 * 16)) ^ swzR;   // kk = 1
  const char* AsB = (const char*)As;
  const char* BsB = (const char*)Bs;

  float sc = 0.f, nszp = 0.f;
  if constexpr (FUSED) { sc = *sp; nszp = -sc * (*zpp); }

  for (int t = 0; t < KT; ++t) {
    if constexpr (!FUSED) {
      // global_load_lds staging: LDS dest linear, global source pre-swizzled.
      // lane -> (row sub = lane>>3, chunk = lane&7); chunk' = chunk ^ (r&7).
      const unsigned short* gA =
          (const unsigned short*)Ap + (size_t)(mt * BM) * K_DIM + t * BK;
      const unsigned short* gB =
          (const unsigned short*)Bp + (size_t)(nt * BN) * K_DIM + t * BK;
      const int rsub = lane >> 3;
      const int csw  = ((lane & 7) ^ rsub) * 8;  // elements
#pragma unroll
      for (int c = 0; c < 4; ++c) {
        const int r0 = wave * 32 + c * 8;
        __builtin_amdgcn_global_load_lds(
            (const __attribute__((address_space(1))) void*)(
                gA + (size_t)(r0 + rsub) * K_DIM + csw),
            (__attribute__((address_space(3))) void*)(&As[r0 * BK]), 16, 0, 0);
      }
#pragma unroll
      for (int c = 0; c < 4; ++c) {
        const int r0 = wave * 32 + c * 8;
        __builtin_amdgcn_global_load_lds(
            (const __attribute__((address_space(1))) void*)(
                gB + (size_t)(r0 + rsub) * K_DIM + csw),
            (__attribute__((address_space(3))) void*)(&Bs[r0 * BK]), 16, 0, 0);
      }
    } else {
      // Fused path: reg-stage with conversion, swizzled ds_write (8B stores).
      const float* gx = (const float*)Ap;
      const int*   gq = (const int*)Bp;
#pragma unroll
      for (int i = 0; i < 8; ++i) {
        const int c = i * 256 + tid;          // 0..2047
        const int row = c >> 4, col = (c & 15) * 4;
        float4 v = *(const float4*)(gx + (size_t)(mt * BM + row) * K_DIM + t * BK + col);
        ushort4 o = make_ushort4(f2bf(v.x), f2bf(v.y), f2bf(v.z), f2bf(v.w));
        const unsigned off = (unsigned)row * (BK * 2) +
                             (((unsigned)col * 2) ^ (((unsigned)(row & 7)) << 4));
        *(ushort4*)((char*)As + off) = o;
      }
#pragma unroll
      for (int i = 0; i < 8; ++i) {
        const int c = i * 256 + tid;
        const int row = c >> 4, col = (c & 15) * 4;
        int4 v = *(const int4*)(gq + (size_t)(nt * BN + row) * K_DIM + t * BK + col);
        ushort4 o = make_ushort4(f2bf(fmaf(sc, (float)v.x, nszp)),
                                 f2bf(fmaf(sc, (float)v.y, nszp)),
                                 f2bf(fmaf(sc, (float)v.z, nszp)),
                                 f2bf(fmaf(sc, (float)v.w, nszp)));
        const unsigned off = (unsigned)row * (BK * 2) +
                             (((unsigned)col * 2) ^ (((unsigned)(row & 7)) << 4));
        *(ushort4*)((char*)Bs + off) = o;
      }
    }
    __syncthreads();   // staging complete (drains vmcnt for gload_lds)

#pragma unroll
    for (int kk = 0; kk < 2; ++kk) {
      const unsigned kc = kk ? kc1 : kc0;
      short8 af[4], bfr[4];
#pragma unroll
      for (int m = 0; m < 4; ++m)
        af[m] = *(const short8*)(AsB + aBase + m * (16 * BK * 2) + kc);
#pragma unroll
      for (int n = 0; n < 4; ++n)
        bfr[n] = *(const short8*)(BsB + bBase + n * (16 * BK * 2) + kc);
#pragma unroll
      for (int m = 0; m < 4; ++m)
#pragma unroll
        for (int n = 0; n < 4; ++n)
          acc[m][n] = __builtin_amdgcn_mfma_f32_16x16x32_bf16(af[m], bfr[n],
                                                              acc[m][n], 0, 0, 0);
    }
    __syncthreads();   // compute done before next overwrite
  }

  // Epilogue. Verified C/D map: col = lane&15 (N), row = (lane>>4)*4 + reg (M).
  const int grow = mt * BM + wr * 64 + l4 * 4;
  const int gcol = nt * BN + wc * 64 + l15;
#pragma unroll
  for (int m = 0; m < 4; ++m)
#pragma unroll
    for (int n = 0; n < 4; ++n)
#pragma unroll
      for (int j = 0; j < 4; ++j)
        C[(size_t)(grow + m * 16 + j) * N_DIM + (gcol + n * 16)] = acc[m][n][j];
}

extern "C" void kernel_launch(void* const* d_in, const int* in_sizes, int n_in,
                              void* d_out, int out_size, void* d_ws, size_t ws_size,
                              hipStream_t stream) {
  const float* x   = (const float*)d_in[0];
  const int*   wq  = (const int*)d_in[1];
  const float* sp  = (const float*)d_in[2];
  const float* zpp = (const float*)d_in[3];
  float* out = (float*)d_out;

  const size_t wbytes = (size_t)N_DIM * K_DIM * sizeof(unsigned short);  // 90.2 MB
  const size_t xbytes = (size_t)M_DIM * K_DIM * sizeof(unsigned short);  // 33.6 MB
  const int grid = (M_DIM / BM) * NTILES_N;  // 32 * 86 = 2752

  if (ws_size >= wbytes + xbytes) {
    unsigned short* wb = (unsigned short*)d_ws;
    unsigned short* xb = (unsigned short*)((char*)d_ws + wbytes);
    cvt_w_kernel<<<2048, 256, 0, stream>>>(wq, wb, sp, zpp,
                                           (int)((size_t)N_DIM * K_DIM / 4));
    cvt_x_kernel<<<2048, 256, 0, stream>>>(x, xb,
                                           (int)((size_t)M_DIM * K_DIM / 4));
    qgemm<false><<<grid, 256, 0, stream>>>(xb, wb, sp, zpp, out);
  } else {
    qgemm<true><<<grid, 256, 0, stream>>>(x, wq, sp, zpp, out);
  }
}

// Round 2
// 399.220 us; speedup vs baseline: 1.4150x; 1.4150x over previous
//
#include <hip/hip_runtime.h>

// QuantizedLinear: out[M=4096, N=11008] = x[M,K=4096] @ (s*(q-zp))[N,K]^T
// Round 2: preconvert x,w -> bf16 in d_ws (unchanged), then 256x256 8-phase
// pipelined MFMA GEMM (T2 swizzle + T3/T4 counted-vmcnt phases + T5 setprio).

#define M_DIM 4096
#define N_DIM 11008
#define K_DIM 4096
#define KT 64              // K_DIM / 64 K-tiles
#define NT_N 43            // N_DIM / 256
#define NT_M 16            // M_DIM / 256

typedef __attribute__((ext_vector_type(8))) short short8;  // 8 x bf16
typedef __attribute__((ext_vector_type(4))) float f32x4;

__device__ inline unsigned short f2bf(float f) {
  unsigned int u = __float_as_uint(f);
  u += 0x7FFFu + ((u >> 16) & 1u);
  return (unsigned short)(u >> 16);
}

// ---- conversion pre-passes ----

__global__ void cvt_w_kernel(const int* __restrict__ q, unsigned short* __restrict__ wb,
                             const float* __restrict__ sp, const float* __restrict__ zpp,
                             int n4) {
  const float s = *sp;
  const float nszp = -s * (*zpp);
  int stride = gridDim.x * blockDim.x;
  for (int i = blockIdx.x * blockDim.x + threadIdx.x; i < n4; i += stride) {
    int4 v = ((const int4*)q)[i];
    ushort4 o = make_ushort4(f2bf(fmaf(s, (float)v.x, nszp)),
                             f2bf(fmaf(s, (float)v.y, nszp)),
                             f2bf(fmaf(s, (float)v.z, nszp)),
                             f2bf(fmaf(s, (float)v.w, nszp)));
    ((ushort4*)wb)[i] = o;
  }
}

__global__ void cvt_x_kernel(const float* __restrict__ x, unsigned short* __restrict__ xb,
                             int n4) {
  int stride = gridDim.x * blockDim.x;
  for (int i = blockIdx.x * blockDim.x + threadIdx.x; i < n4; i += stride) {
    float4 v = ((const float4*)x)[i];
    ushort4 o = make_ushort4(f2bf(v.x), f2bf(v.y), f2bf(v.z), f2bf(v.w));
    ((ushort4*)xb)[i] = o;
  }
}

// ---- 256x256 8-phase GEMM ----
// LDS regions (shorts): A(d,h) = d*32768 + h*8192 ; B(d,h) = d*32768 + 16384 + h*8192
// Half-tile = 128 rows x 64 cols bf16 = 16KB. Swizzle: elem (r,k) at byte
// r*128 + ((k*2) ^ ((r&7)<<4)); staged linearly via global_load_lds with the
// inverse-swizzled global source (round-1-verified involution).

__device__ __forceinline__ void stage_half(const unsigned short* __restrict__ gsrc,
                                           unsigned short* ldsBase, int w, int lane) {
  const int rsub = lane >> 3;
  const int csw  = ((lane & 7) ^ rsub) << 3;  // elements
#pragma unroll
  for (int r = 0; r < 2; ++r) {
    __builtin_amdgcn_global_load_lds(
        (const __attribute__((address_space(1))) void*)(
            gsrc + (size_t)(r * 64 + w * 8 + rsub) * K_DIM + csw),
        (__attribute__((address_space(3))) void*)(ldsBase + r * 4096 + w * 512),
        16, 0, 0);
  }
}

#define DS_A(d, mh)                                                                 \
  do {                                                                              \
    _Pragma("unroll") for (int mi = 0; mi < 4; ++mi) {                              \
      _Pragma("unroll") for (int kk = 0; kk < 2; ++kk) {                            \
        a_frag[mi][kk] = *(const short8*)(ldsB + (d) * 65536 + aHalfByte +          \
                                          aRowByte + ((mh) * 4 + mi) * 2048 +       \
                                          kc[kk]);                                  \
      }                                                                             \
    }                                                                               \
  } while (0)

#define DS_B2(d, nh)                                                                \
  do {                                                                              \
    _Pragma("unroll") for (int ni = 0; ni < 2; ++ni) {                              \
      _Pragma("unroll") for (int kk = 0; kk < 2; ++kk) {                            \
        b_frag[(nh) * 2 + ni][kk] =                                                 \
            *(const short8*)(ldsB + (d) * 65536 + bHalfByte + bRowByte +            \
                             ((nh) * 2 + ni) * 2048 + kc[kk]);                      \
      }                                                                             \
    }                                                                               \
  } while (0)

#define MFMA_QUAD(mh, nh)                                                           \
  do {                                                                              \
    __builtin_amdgcn_s_setprio(1);                                                  \
    _Pragma("unroll") for (int mi = 0; mi < 4; ++mi) {                              \
      _Pragma("unroll") for (int ni = 0; ni < 2; ++ni) {                            \
        _Pragma("unroll") for (int kk = 0; kk < 2; ++kk) {                          \
          acc[(mh) * 4 + mi][(nh) * 2 + ni] =                                       \
              __builtin_amdgcn_mfma_f32_16x16x32_bf16(                              \
                  a_frag[mi][kk], b_frag[(nh) * 2 + ni][kk],                        \
                  acc[(mh) * 4 + mi][(nh) * 2 + ni], 0, 0, 0);                      \
        }                                                                           \
      }                                                                             \
    }                                                                               \
    __builtin_amdgcn_s_setprio(0);                                                  \
  } while (0)

#define PHASE_SYNC()                                                                \
  do {                                                                              \
    __builtin_amdgcn_s_barrier();                                                   \
    asm volatile("s_waitcnt lgkmcnt(0)" ::: "memory");                              \
    __builtin_amdgcn_sched_barrier(0);                                              \
  } while (0)

#define PHASE_END() __builtin_amdgcn_s_barrier()
#define VMC4() asm volatile("s_waitcnt vmcnt(4)" ::: "memory")

__global__ __launch_bounds__(512, 2) void qgemm8(const unsigned short* __restrict__ Abf,
                                                 const unsigned short* __restrict__ Wbf,
                                                 float* __restrict__ C) {
  __shared__ unsigned short lds[65536];  // 128 KiB

  // bijective XCD swizzle: 688 = 8 * 86
  int bid = blockIdx.x;
  {
    const int cpx = (NT_M * NT_N) >> 3;  // 86
    bid = (bid & 7) * cpx + (bid >> 3);
  }
  const int mt = bid / NT_N;
  const int nt = bid % NT_N;

  const int tid  = threadIdx.x;
  const int w    = tid >> 6;
  const int lane = tid & 63;
  const int l15  = lane & 15;
  const int l4   = lane >> 4;
  const int wr   = w >> 2;   // 0..1 -> 128 output rows
  const int wc   = w & 3;    // 0..3 -> 64 output cols

  const unsigned short* gA = Abf + (size_t)(mt * 256) * K_DIM;
  const unsigned short* gB = Wbf + (size_t)(nt * 256) * K_DIM;

  const char* ldsB = (const char*)lds;
  const unsigned aHalfByte = (unsigned)wr * 16384u;
  const unsigned bHalfByte = 32768u + (unsigned)(wc >> 1) * 16384u;
  const unsigned aRowByte  = (unsigned)l15 * 128u;
  const unsigned bRowByte  = (unsigned)((wc & 1) * 64 + l15) * 128u;
  const unsigned swz       = (unsigned)(l15 & 7) << 4;
  const unsigned kc[2]     = {((unsigned)(l4 * 16)) ^ swz,
                              ((unsigned)(64 + l4 * 16)) ^ swz};

  short8 a_frag[4][2];
  short8 b_frag[4][2];
  f32x4 acc[8][4];
#pragma unroll
  for (int m = 0; m < 8; ++m)
#pragma unroll
    for (int n = 0; n < 4; ++n) acc[m][n] = (f32x4)0.0f;

  // Prologue: B0(0) B1(0) A0(0) A1(0) B0(1) B1(1)  (12 loads/thread)
  stage_half(gB, lds + 16384, w, lane);
  stage_half(gB + (size_t)128 * K_DIM, lds + 24576, w, lane);
  stage_half(gA, lds + 0, w, lane);
  stage_half(gA + (size_t)128 * K_DIM, lds + 8192, w, lane);
  stage_half(gB + 64, lds + 49152, w, lane);
  stage_half(gB + (size_t)128 * K_DIM + 64, lds + 57344, w, lane);
  VMC4();  // tile 0 (d0) fully landed; B(1) may still be in flight
  __builtin_amdgcn_s_barrier();

#pragma unroll 1
  for (int i = 0; i < KT / 2; ++i) {
    const int t1 = 2 * i + 1;
    const int c2 = (2 * i + 2 < KT) ? 2 * i + 2 : KT - 1;  // clamped tail (dead writes)
    const int c3 = (2 * i + 3 < KT) ? 2 * i + 3 : KT - 1;

    // ph1: quad(d0,mh0,nh0); stage A0(t1)->d1
    DS_A(0, 0);
    DS_B2(0, 0);
    stage_half(gA + (size_t)t1 * 64, lds + 32768, w, lane);
    PHASE_SYNC();
    MFMA_QUAD(0, 0);
    PHASE_END();

    // ph2: quad(d0,mh0,nh1); stage A1(t1)->d1
    DS_B2(0, 1);
    stage_half(gA + (size_t)128 * K_DIM + (size_t)t1 * 64, lds + 40960, w, lane);
    PHASE_SYNC();
    MFMA_QUAD(0, 1);
    PHASE_END();

    // ph3: quad(d0,mh1,nh1); stage B0(c2)->d0 (B last read ph2)
    DS_A(0, 1);
    stage_half(gB + (size_t)c2 * 64, lds + 16384, w, lane);
    PHASE_SYNC();
    MFMA_QUAD(1, 1);
    PHASE_END();

    // ph4: quad(d0,mh1,nh0); stage B1(c2)->d0; vmcnt(4) -> t1 (d1) landed
    stage_half(gB + (size_t)128 * K_DIM + (size_t)c2 * 64, lds + 24576, w, lane);
    PHASE_SYNC();
    MFMA_QUAD(1, 0);
    VMC4();
    PHASE_END();

    // ph5: quad(d1,mh0,nh0); stage A0(c2)->d0 (A(d0) last read ph3)
    DS_A(1, 0);
    DS_B2(1, 0);
    stage_half(gA + (size_t)c2 * 64, lds + 0, w, lane);
    PHASE_SYNC();
    MFMA_QUAD(0, 0);
    PHASE_END();

    // ph6: quad(d1,mh0,nh1); stage A1(c2)->d0
    DS_B2(1, 1);
    stage_half(gA + (size_t)128 * K_DIM + (size_t)c2 * 64, lds + 8192, w, lane);
    PHASE_SYNC();
    MFMA_QUAD(0, 1);
    PHASE_END();

    // ph7: quad(d1,mh1,nh1); stage B0(c3)->d1 (B(d1) last read ph6)
    DS_A(1, 1);
    stage_half(gB + (size_t)c3 * 64, lds + 49152, w, lane);
    PHASE_SYNC();
    MFMA_QUAD(1, 1);
    PHASE_END();

    // ph8: quad(d1,mh1,nh0); stage B1(c3)->d1; vmcnt(4) -> c2 (d0) landed
    stage_half(gB + (size_t)128 * K_DIM + (size_t)c3 * 64, lds + 57344, w, lane);
    PHASE_SYNC();
    MFMA_QUAD(1, 0);
    VMC4();
    PHASE_END();
  }

  // Epilogue: verified C/D map col=lane&15, row=(lane>>4)*4+reg
  const int grow = mt * 256 + wr * 128 + l4 * 4;
  const int gcol = nt * 256 + wc * 64 + l15;
#pragma unroll
  for (int ma = 0; ma < 8; ++ma)
#pragma unroll
    for (int n = 0; n < 4; ++n)
#pragma unroll
      for (int j = 0; j < 4; ++j)
        C[(size_t)(grow + ma * 16 + j) * N_DIM + (gcol + n * 16)] = acc[ma][n][j];
}

// ---- fallback: round-1 fused 128x128 kernel (only if ws too small) ----

__global__ __launch_bounds__(256) void qgemm_fused(const float* __restrict__ Ap,
                                                   const int* __restrict__ Bp,
                                                   const float* __restrict__ sp,
                                                   const float* __restrict__ zpp,
                                                   float* __restrict__ C) {
  __shared__ unsigned short As[128 * 64];
  __shared__ unsigned short Bs[128 * 64];
  int bid = blockIdx.x;
  {
    const int nwg = gridDim.x;
    if ((nwg & 7) == 0) bid = (bid & 7) * (nwg >> 3) + (bid >> 3);
  }
  const int mt = bid / (N_DIM / 128);
  const int nt = bid % (N_DIM / 128);
  const int tid = threadIdx.x, wave = tid >> 6, lane = tid & 63;
  const int l15 = lane & 15, l4 = lane >> 4, wr = wave >> 1, wcc = wave & 1;
  f32x4 acc[4][4];
#pragma unroll
  for (int m = 0; m < 4; ++m)
#pragma unroll
    for (int n = 0; n < 4; ++n) acc[m][n] = (f32x4)0.0f;
  const unsigned swz = (unsigned)(lane & 7) << 4;
  const unsigned aBase = (unsigned)(wr * 64 + l15) * 128;
  const unsigned bBase = (unsigned)(wcc * 64 + l15) * 128;
  const unsigned kc0 = ((unsigned)(l4 * 16)) ^ swz;
  const unsigned kc1 = ((unsigned)(64 + l4 * 16)) ^ swz;
  const char* AsB = (const char*)As;
  const char* BsB = (const char*)Bs;
  const float sc = *sp;
  const float nszp = -sc * (*zpp);
  for (int t = 0; t < K_DIM / 64; ++t) {
#pragma unroll
    for (int i = 0; i < 8; ++i) {
      const int c = i * 256 + tid;
      const int row = c >> 4, col = (c & 15) * 4;
      float4 v = *(const float4*)(Ap + (size_t)(mt * 128 + row) * K_DIM + t * 64 + col);
      ushort4 o = make_ushort4(f2bf(v.x), f2bf(v.y), f2bf(v.z), f2bf(v.w));
      const unsigned off = (unsigned)row * 128 +
                           (((unsigned)col * 2) ^ (((unsigned)(row & 7)) << 4));
      *(ushort4*)((char*)As + off) = o;
    }
#pragma unroll
    for (int i = 0; i < 8; ++i) {
      const int c = i * 256 + tid;
      const int row = c >> 4, col = (c & 15) * 4;
      int4 v = *(const int4*)(Bp + (size_t)(nt * 128 + row) * K_DIM + t * 64 + col);
      ushort4 o = make_ushort4(f2bf(fmaf(sc, (float)v.x, nszp)),
                               f2bf(fmaf(sc, (float)v.y, nszp)),
                               f2bf(fmaf(sc, (float)v.z, nszp)),
                               f2bf(fmaf(sc, (float)v.w, nszp)));
      const unsigned off = (unsigned)row * 128 +
                           (((unsigned)col * 2) ^ (((unsigned)(row & 7)) << 4));
      *(ushort4*)((char*)Bs + off) = o;
    }
    __syncthreads();
#pragma unroll
    for (int kk = 0; kk < 2; ++kk) {
      const unsigned kcx = kk ? kc1 : kc0;
      short8 af[4], bfr[4];
#pragma unroll
      for (int m = 0; m < 4; ++m) af[m] = *(const short8*)(AsB + aBase + m * 2048 + kcx);
#pragma unroll
      for (int n = 0; n < 4; ++n) bfr[n] = *(const short8*)(BsB + bBase + n * 2048 + kcx);
#pragma unroll
      for (int m = 0; m < 4; ++m)
#pragma unroll
        for (int n = 0; n < 4; ++n)
          acc[m][n] = __builtin_amdgcn_mfma_f32_16x16x32_bf16(af[m], bfr[n], acc[m][n], 0, 0, 0);
    }
    __syncthreads();
  }
  const int grow = mt * 128 + wr * 64 + l4 * 4;
  const int gcol = nt * 128 + wcc * 64 + l15;
#pragma unroll
  for (int m = 0; m < 4; ++m)
#pragma unroll
    for (int n = 0; n < 4; ++n)
#pragma unroll
      for (int j = 0; j < 4; ++j)
        C[(size_t)(grow + m * 16 + j) * N_DIM + (gcol + n * 16)] = acc[m][n][j];
}

extern "C" void kernel_launch(void* const* d_in, const int* in_sizes, int n_in,
                              void* d_out, int out_size, void* d_ws, size_t ws_size,
                              hipStream_t stream) {
  const float* x   = (const float*)d_in[0];
  const int*   wq  = (const int*)d_in[1];
  const float* sp  = (const float*)d_in[2];
  const float* zpp = (const float*)d_in[3];
  float* out = (float*)d_out;

  const size_t wbytes = (size_t)N_DIM * K_DIM * sizeof(unsigned short);
  const size_t xbytes = (size_t)M_DIM * K_DIM * sizeof(unsigned short);

  if (ws_size >= wbytes + xbytes) {
    unsigned short* wb = (unsigned short*)d_ws;
    unsigned short* xb = (unsigned short*)((char*)d_ws + wbytes);
    cvt_w_kernel<<<2048, 256, 0, stream>>>(wq, wb, sp, zpp,
                                           (int)((size_t)N_DIM * K_DIM / 4));
    cvt_x_kernel<<<2048, 256, 0, stream>>>(x, xb,
                                           (int)((size_t)M_DIM * K_DIM / 4));
    qgemm8<<<NT_M * NT_N, 512, 0, stream>>>(xb, wb, out);
  } else {
    qgemm_fused<<<(M_DIM / 128) * (N_DIM / 128), 256, 0, stream>>>(x, wq, sp, zpp, out);
  }
}